// Round 1
// baseline (417.138 us; speedup 1.0000x reference)
//
#include <hip/hip_runtime.h>
#include <hip/hip_bf16.h>

// out[m][n] = C[m][n] * D[n];  M = NR = 8192, fp32 in/out.
// Memory-bound broadcast multiply. One float4 per thread, fully coalesced.
// NR/4 = 2048 (power of two) -> column-vector index is (i & 2047).

#define NR 8192
#define M_ROWS 8192

__global__ __launch_bounds__(256) void colscale_kernel(
    const float4* __restrict__ C4,
    const float4* __restrict__ D4,
    float4* __restrict__ O4)
{
    const unsigned i = blockIdx.x * blockDim.x + threadIdx.x;  // float4 index
    const float4 c = C4[i];
    const float4 d = D4[i & (NR / 4 - 1)];   // column block, L1/L2-resident
    float4 o;
    o.x = c.x * d.x;
    o.y = c.y * d.y;
    o.z = c.z * d.z;
    o.w = c.w * d.w;
    O4[i] = o;
}

extern "C" void kernel_launch(void* const* d_in, const int* in_sizes, int n_in,
                              void* d_out, int out_size, void* d_ws, size_t ws_size,
                              hipStream_t stream) {
    const float4* C4 = (const float4*)d_in[0];
    const float4* D4 = (const float4*)d_in[1];
    float4* O4 = (float4*)d_out;

    const int n4 = (M_ROWS * NR) / 4;        // 16,777,216 float4s
    const int threads = 256;
    const int blocks = n4 / threads;         // 65,536 blocks

    colscale_kernel<<<blocks, threads, 0, stream>>>(C4, D4, O4);
}